// Round 17
// baseline (283.008 us; speedup 1.0000x reference)
//
#include <hip/hip_runtime.h>
#include <math.h>

namespace {
constexpr int CDIM   = 128;
constexpr int KCODES = 1024;
constexpr int HWSZ   = 4096;   // 64*64
constexpr int BATCH  = 16;
constexpr int NPOS   = BATCH * HWSZ;            // 65536
constexpr int P      = 256;                     // positions per block
constexpr int NWAVES = 16;                      // 1024 threads
constexpr int KPW    = KCODES / NWAVES;         // 64 codes per wave
constexpr int KT     = 8;                       // codes per inner tile
constexpr int THREADS = 1024;
constexpr size_t QELEMS   = (size_t)BATCH * CDIM * HWSZ;   // 8388608
constexpr size_t IDX_OFF  = QELEMS;                        // float32 elements
constexpr size_t LOSS_OFF = IDX_OFF + (size_t)NPOS;        // 8454144
constexpr size_t PERP_OFF = LOSS_OFF + 1;
// d_ws float-element offsets
constexpr int WS_C2   = 0;      // [0,1024)   float ||c_k||^2 (numpy-bit-exact)
constexpr int WS_HIST = 1024;   // [1024,2048) uint  usage counts
constexpr int WS_LOSS = 2048;   // [2048]     float sum ||z-q||^2
constexpr float INV_TOTAL = 1.0f / (float)QELEMS;
constexpr float INV_NPOS  = 1.0f / (float)NPOS;
}

// ---- pass 0: codebook norms (numpy-bit-exact) + zero accumulators ----------
// Array-free form (rr[128] is this allocator's known spill trap). Same numpy
// pairwise 8-chain order via float4 pairs; __f*_rn forbids fma contraction.
__global__ __launch_bounds__(256) void vq_prep(const float* __restrict__ cb,
                                               float* __restrict__ ws) {
    const int k = blockIdx.x * 256 + threadIdx.x;   // 0..1023
    const float4* row = (const float4*)(cb + (size_t)k * CDIM);
    float r[8];
    {
        const float4 a = row[0], b = row[1];
        r[0] = __fmul_rn(a.x, a.x); r[1] = __fmul_rn(a.y, a.y);
        r[2] = __fmul_rn(a.z, a.z); r[3] = __fmul_rn(a.w, a.w);
        r[4] = __fmul_rn(b.x, b.x); r[5] = __fmul_rn(b.y, b.y);
        r[6] = __fmul_rn(b.z, b.z); r[7] = __fmul_rn(b.w, b.w);
    }
    #pragma unroll
    for (int m = 1; m < CDIM / 8; ++m) {
        const float4 a = row[2 * m], b = row[2 * m + 1];
        r[0] = __fadd_rn(r[0], __fmul_rn(a.x, a.x));
        r[1] = __fadd_rn(r[1], __fmul_rn(a.y, a.y));
        r[2] = __fadd_rn(r[2], __fmul_rn(a.z, a.z));
        r[3] = __fadd_rn(r[3], __fmul_rn(a.w, a.w));
        r[4] = __fadd_rn(r[4], __fmul_rn(b.x, b.x));
        r[5] = __fadd_rn(r[5], __fmul_rn(b.y, b.y));
        r[6] = __fadd_rn(r[6], __fmul_rn(b.z, b.z));
        r[7] = __fadd_rn(r[7], __fmul_rn(b.w, b.w));
    }
    const float s01 = __fadd_rn(r[0], r[1]);
    const float s23 = __fadd_rn(r[2], r[3]);
    const float s45 = __fadd_rn(r[4], r[5]);
    const float s67 = __fadd_rn(r[6], r[7]);
    ws[WS_C2 + k] = __fadd_rn(__fadd_rn(s01, s23), __fadd_rn(s45, s67));
    ((unsigned int*)ws)[WS_HIST + k] = 0u;
    if (k == 0) ws[WS_LOSS] = 0.0f;
}

// ---- pass 1: codes via SGPR, z via LDS, 2-chunk batched drains -------------
// Round 17. R16 (64 accs, 512-FMA unrolled region) killed the container twice
// — same signature as R5 (64 accs, 512-FMA region, died twice); every 32-acc/
// <=256-FMA kernel compiled. Theory: scheduler blowup on the big region. This
// round gets R16's GOAL (512cy of work per lgkmcnt drain) within the proven
// envelope: R15 shape (32 accs, 4 pos x KT=8, 1024 thr, P=256) but the c4
// loop steps by 2, issuing BOTH chunks' loads (8 ds_read_b128 + 16
// s_load_dwordx4) before BOTH 128-FMA blocks. Mixed DS+SMEM forces a full
// drain anyway -> one drain now covers 256 FMA insts = 512cy. Fitted
// L(16 s_loads) ~ 1400cy -> util = 4x512/(512+1400) ~ saturation. Regs:
// 32 acc + 32 zv VGPR (~90 total, <=128 so the 16-wave block launches);
// cvA+cvB = 64 SGPR. Region = 256 FMAs, #pragma unroll 1.
// Bit-exactness: chunk A = channels 4c4..4c4+3, chunk B = 4c4+4..4c4+7 ->
// each (pos,code) chain strictly ascending-c; z2 numpy pairwise 8-chain;
// d = fl(fl(z2-2zc)+c2); strict-< ascending k (j in tile, tiles, strips all
// ascend); cross-wave lexicographic (d,k) min == np.argmin first-index.
__global__ __launch_bounds__(1024, 1) void vq_main(const float* __restrict__ z,
                                                   const float* __restrict__ cb,
                                                   float* __restrict__ ws,
                                                   float* __restrict__ out) {
    __shared__ __align__(16) float zt[CDIM][P];     // 128 KB  zt[c][p]
    __shared__ float z2s[P];                        // 1 KB
    __shared__ float bdls[NWAVES][P];               // 16 KB  per-wave best_d
    __shared__ unsigned short bkls[NWAVES][P];      // 8 KB   per-wave best_k
    __shared__ unsigned short wkls[P];              // 512 B  winning code
    __shared__ float red[P];                        // 1 KB   (total ~154.5 KB)

    const int tid   = threadIdx.x;
    const int nbase = blockIdx.x * P;
    const int b     = nbase >> 12;          // 4096 positions per batch image
    const int hw0   = nbase & (HWSZ - 1);   // 256-aligned
    const float* zb = z + (size_t)b * CDIM * HWSZ + hw0;

    // ---- stage z strip: zt[c][p] = z[b][c][hw0+p] (coalesced) --------------
    #pragma unroll
    for (int i = 0; i < (CDIM * P / 4) / THREADS; ++i) {   // 8 iters
        const int linear = i * THREADS + tid;              // 0..8191
        const int c  = linear >> 6;                        // 64 float4 per row
        const int p4 = (linear & 63) * 4;
        *(float4*)&zt[c][p4] = *(const float4*)(zb + (size_t)c * HWSZ + p4);
    }
    __syncthreads();

    // ---- z2 per position: numpy pairwise 8-chain, streamed from LDS --------
    if (tid < P) {
        const int p = tid;
        float r[8];
        #pragma unroll
        for (int j = 0; j < 8; ++j) {
            const float x = zt[j][p];
            r[j] = __fmul_rn(x, x);
        }
        #pragma unroll
        for (int i = 8; i < CDIM; i += 8) {
            #pragma unroll
            for (int j = 0; j < 8; ++j) {
                const float x = zt[i + j][p];
                r[j] = __fadd_rn(r[j], __fmul_rn(x, x));
            }
        }
        const float s01 = __fadd_rn(r[0], r[1]);
        const float s23 = __fadd_rn(r[2], r[3]);
        const float s45 = __fadd_rn(r[4], r[5]);
        const float s67 = __fadd_rn(r[6], r[7]);
        z2s[p] = __fadd_rn(__fadd_rn(s01, s23), __fadd_rn(s45, s67));
    }
    __syncthreads();

    const int lane = tid & 63;
    const int p0   = lane * 4;              // each lane owns 4 positions
    // readfirstlane makes the wave id PROVABLY scalar -> all code addresses
    // derived from it are scalar -> compiler emits s_load (SGPR destination).
    const int wid  = __builtin_amdgcn_readfirstlane(tid >> 6);
    const int kw   = wid * KPW;             // wave's contiguous code strip
    const float* c2g = ws + WS_C2;

    float z2r[4];
    #pragma unroll
    for (int i = 0; i < 4; ++i) z2r[i] = z2s[p0 + i];

    float bestd[4] = {INFINITY, INFINITY, INFINITY, INFINITY};
    int   bestk[4] = {0, 0, 0, 0};

    // ---- main loop: NO barriers; 2 chunks of loads per drain window --------
    for (int ht = 0; ht < KPW / KT; ++ht) {        // 8 tiles of 8 codes
        const int kb = kw + ht * KT;
        const float* ctile = cb + (size_t)kb * CDIM;  // scalar base

        float a[4][KT];
        #pragma unroll
        for (int i = 0; i < 4; ++i)
            #pragma unroll
            for (int j = 0; j < KT; ++j) a[i][j] = 0.0f;

        #pragma unroll 1
        for (int c4 = 0; c4 < CDIM / 4; c4 += 2) {
            const int cA = c4 * 4;
            const int cB = cA + 4;
            // ---- issue ALL loads for both chunks first ---------------------
            const float4 zA0 = *(const float4*)&zt[cA + 0][p0];
            const float4 zA1 = *(const float4*)&zt[cA + 1][p0];
            const float4 zA2 = *(const float4*)&zt[cA + 2][p0];
            const float4 zA3 = *(const float4*)&zt[cA + 3][p0];
            const float4 zB0 = *(const float4*)&zt[cB + 0][p0];
            const float4 zB1 = *(const float4*)&zt[cB + 1][p0];
            const float4 zB2 = *(const float4*)&zt[cB + 2][p0];
            const float4 zB3 = *(const float4*)&zt[cB + 3][p0];
            float4 cvA[KT], cvB[KT];   // scalar (SGPR), wave-uniform
            #pragma unroll
            for (int j = 0; j < KT; ++j)
                cvA[j] = *(const float4*)(ctile + (size_t)j * CDIM + cA);
            #pragma unroll
            for (int j = 0; j < KT; ++j)
                cvB[j] = *(const float4*)(ctile + (size_t)j * CDIM + cB);
            // ---- chunk A: channels cA..cA+3 (ascending) --------------------
            #pragma unroll
            for (int j = 0; j < KT; ++j) {
                a[0][j] = fmaf(zA0.x, cvA[j].x, a[0][j]);
                a[0][j] = fmaf(zA1.x, cvA[j].y, a[0][j]);
                a[0][j] = fmaf(zA2.x, cvA[j].z, a[0][j]);
                a[0][j] = fmaf(zA3.x, cvA[j].w, a[0][j]);
                a[1][j] = fmaf(zA0.y, cvA[j].x, a[1][j]);
                a[1][j] = fmaf(zA1.y, cvA[j].y, a[1][j]);
                a[1][j] = fmaf(zA2.y, cvA[j].z, a[1][j]);
                a[1][j] = fmaf(zA3.y, cvA[j].w, a[1][j]);
                a[2][j] = fmaf(zA0.z, cvA[j].x, a[2][j]);
                a[2][j] = fmaf(zA1.z, cvA[j].y, a[2][j]);
                a[2][j] = fmaf(zA2.z, cvA[j].z, a[2][j]);
                a[2][j] = fmaf(zA3.z, cvA[j].w, a[2][j]);
                a[3][j] = fmaf(zA0.w, cvA[j].x, a[3][j]);
                a[3][j] = fmaf(zA1.w, cvA[j].y, a[3][j]);
                a[3][j] = fmaf(zA2.w, cvA[j].z, a[3][j]);
                a[3][j] = fmaf(zA3.w, cvA[j].w, a[3][j]);
            }
            // ---- chunk B: channels cB..cB+3 (ascending) --------------------
            #pragma unroll
            for (int j = 0; j < KT; ++j) {
                a[0][j] = fmaf(zB0.x, cvB[j].x, a[0][j]);
                a[0][j] = fmaf(zB1.x, cvB[j].y, a[0][j]);
                a[0][j] = fmaf(zB2.x, cvB[j].z, a[0][j]);
                a[0][j] = fmaf(zB3.x, cvB[j].w, a[0][j]);
                a[1][j] = fmaf(zB0.y, cvB[j].x, a[1][j]);
                a[1][j] = fmaf(zB1.y, cvB[j].y, a[1][j]);
                a[1][j] = fmaf(zB2.y, cvB[j].z, a[1][j]);
                a[1][j] = fmaf(zB3.y, cvB[j].w, a[1][j]);
                a[2][j] = fmaf(zB0.z, cvB[j].x, a[2][j]);
                a[2][j] = fmaf(zB1.z, cvB[j].y, a[2][j]);
                a[2][j] = fmaf(zB2.z, cvB[j].z, a[2][j]);
                a[2][j] = fmaf(zB3.z, cvB[j].w, a[2][j]);
                a[3][j] = fmaf(zB0.w, cvB[j].x, a[3][j]);
                a[3][j] = fmaf(zB1.w, cvB[j].y, a[3][j]);
                a[3][j] = fmaf(zB2.w, cvB[j].z, a[3][j]);
                a[3][j] = fmaf(zB3.w, cvB[j].w, a[3][j]);
            }
        }

        // d = fl(fl(z2 - 2*zc) + c2); strict < with ascending k
        #pragma unroll
        for (int j = 0; j < KT; ++j) {
            const float c2 = c2g[kb + j];
            #pragma unroll
            for (int i = 0; i < 4; ++i) {
                const float d = __fadd_rn(fmaf(-2.0f, a[i][j], z2r[i]), c2);
                if (d < bestd[i]) { bestd[i] = d; bestk[i] = kb + j; }
            }
        }
    }

    // ---- per-wave results: wave wid covers all 256 positions ---------------
    #pragma unroll
    for (int i = 0; i < 4; ++i) {
        bdls[wid][p0 + i] = bestd[i];
        bkls[wid][p0 + i] = (unsigned short)bestk[i];
    }
    __syncthreads();

    // ---- combine 16 disjoint code-strips per position; lexicographic (d,k)
    unsigned int* ghist = (unsigned int*)ws + WS_HIST;
    if (tid < P) {
        const int p = tid;
        float bd = bdls[0][p];
        int   bk = bkls[0][p];
        #pragma unroll
        for (int g = 1; g < NWAVES; ++g) {
            const float d = bdls[g][p];
            const int   k = bkls[g][p];
            if (d < bd || (d == bd && k < bk)) { bd = d; bk = k; }
        }
        wkls[p] = (unsigned short)bk;
        out[IDX_OFF + (size_t)(nbase + p)] = (float)bk;
        atomicAdd(&ghist[bk], 1u);       // 256/block, 1024 bins: low contention
        red[p] = bd;       // best_d == fl(||z-q||^2), loss has 2% slack
    }
    __syncthreads();
    for (int s = P / 2; s > 0; s >>= 1) {
        if (tid < s) red[tid] += red[tid + s];
        __syncthreads();
    }
    if (tid == 0) atomicAdd(&ws[WS_LOSS], red[0]);

    // ---- quantized output: out[b][c][hw0+p] = cb[wk[p]][c] -----------------
    // stores coalesced (1024B per c-row); cb gather L1/L2-hot.
    float* ob = out + (size_t)b * CDIM * HWSZ + hw0;
    #pragma unroll
    for (int i = 0; i < (CDIM * P) / THREADS; ++i) {   // 32 iters
        const int linear = i * THREADS + tid;          // 0..32767
        const int c = linear >> 8;
        const int p = linear & 255;
        ob[(size_t)c * HWSZ + p] = cb[(size_t)wkls[p] * CDIM + c];
    }
}

// ---- pass 2: scalars --------------------------------------------------------
__global__ __launch_bounds__(1024) void vq_final(const float* __restrict__ ws,
                                                 float* __restrict__ out) {
    __shared__ float red[1024];
    const int t = threadIdx.x;
    const unsigned int* hist = (const unsigned int*)ws + WS_HIST;
    const float p = (float)hist[t] * INV_NPOS;
    red[t] = p * logf(p + 1e-10f);
    __syncthreads();
    for (int s = 512; s > 0; s >>= 1) {
        if (t < s) red[t] += red[t + s];
        __syncthreads();
    }
    if (t == 0) {
        out[LOSS_OFF] = 1.25f * (ws[WS_LOSS] * INV_TOTAL);   // cb + 0.25*commit
        out[PERP_OFF] = expf(-red[0]);
    }
}

extern "C" void kernel_launch(void* const* d_in, const int* in_sizes, int n_in,
                              void* d_out, int out_size, void* d_ws, size_t ws_size,
                              hipStream_t stream) {
    const float* z  = (const float*)d_in[0];
    const float* cb = (const float*)d_in[1];
    float* out = (float*)d_out;
    float* ws  = (float*)d_ws;

    vq_prep <<<KCODES / 256, 256, 0, stream>>>(cb, ws);
    vq_main <<<NPOS / P,     THREADS, 0, stream>>>(z, cb, ws, out);
    vq_final<<<1,           1024, 0, stream>>>(ws, out);
}